// Round 7
// baseline (5598.159 us; speedup 1.0000x reference)
//
#include <hip/hip_runtime.h>

#define T_LEN 262144
#define R_LEN 4000
#define NCH 64
#define NCHUNK 253       // B chunks t in [0,253); T[252] = zeros (clamp target)
#define WBLK 1540        // staged 16B A-blocks per block window
#define SIG_M 49         // sigma(n) = (n>>5) + 49*(n&31), injective (base-49 digits)
#define LDS_BYTES 25088  // 1568 slots x 16B; sigma_max = 48 + 49*31 = 1567
#define QSTEPS 68        // K-steps per wave; 4 waves cover 272 total

typedef __attribute__((ext_vector_type(8))) short bf16x8;
typedef __attribute__((ext_vector_type(16))) float f32x16;

static __device__ __forceinline__ unsigned short f2bf(float f) {
  unsigned u = __builtin_bit_cast(unsigned, f);
  unsigned r = 0x7FFFu + ((u >> 16) & 1u);
  return (unsigned short)((u + r) >> 16);
}

// T[t][j,h,e] = k[4000 + j - 16t - 8h - e] (zero outside [0,4000))
// stored: btf[((ch*253 + t)*64 + lane)*8 + e], j = lane&31, h = lane>>5
__global__ __launch_bounds__(256) void build_btf(const float* __restrict__ src,
                                                 unsigned short* __restrict__ btf) {
  int t0 = blockIdx.x * 256 + threadIdx.x;
  if (t0 >= NCH * NCHUNK * 64) return;
  int lane = t0 & 63;
  int t = (t0 >> 6) % NCHUNK;
  int ch = t0 / (64 * NCHUNK);
  int j = lane & 31;
  int h = lane >> 5;
  int kbase = 4000 + j - 16 * t - 8 * h;
  const float* k = src + (size_t)ch * R_LEN;
  unsigned short vals[8];
#pragma unroll
  for (int e = 0; e < 8; ++e) {
    int r = kbase - e;
    float f = (r >= 0 && r < R_LEN) ? k[r] : 0.0f;
    vals[e] = f2bf(f);
  }
  unsigned int* dst = (unsigned int*)(btf + (size_t)t0 * 8);
  dst[0] = (unsigned int)vals[0] | ((unsigned int)vals[1] << 16);
  dst[1] = (unsigned int)vals[2] | ((unsigned int)vals[3] << 16);
  dst[2] = (unsigned int)vals[4] | ((unsigned int)vals[5] << 16);
  dst[3] = (unsigned int)vals[6] | ((unsigned int)vals[7] << 16);
}

// Block (256 thr, 4 waves): ch = bid&63, piece = bid>>6 (32 pieces), T0 = piece*8192.
// K-SPLIT: all 4 waves compute the SAME 8192 outputs out[T0 + 256i + 32c + j],
// wave w owns K-steps q in [68w, 68w+68). D_c[i][j] = sum_q A_q[i] . T[q-2c].
// A frag (i=lane&31, h): x[T0-4000+256i+16q+8h+e]; block n = 32i + 2q + h staged at
// sigma(n) = (n>>5)+49*(n&31) -> wave A-reads = 2x contiguous 512B (conflict-free).
// Main loop barrier-free, 8-MFMA clusters under setprio; B from global (L2).
// Epilogue: 4-way partial-sum reduction through LDS (reuses A window).
__global__ __launch_bounds__(256, 6) void conv_main(const float* __restrict__ x,
                                                    const unsigned short* __restrict__ btf,
                                                    float* __restrict__ out) {
  __shared__ alignas(16) unsigned char xs[LDS_BYTES];
  const int bid = blockIdx.x;
  const int ch = bid & 63;          // pieces of a channel share bid%64 -> L2 locality for btf
  const int T0 = (bid >> 6) << 13;
  const float* xch = x + (size_t)ch * T_LEN;
  const char* btc = (const char*)btf + (size_t)ch * NCHUNK * 1024;

  const int tid = threadIdx.x;
  const int lane = tid & 63;
  const int w = tid >> 6;

  // ---- A staging: block n (8 elems at x[T0-4000+8n]) -> LDS slot sigma(n)
  for (int n = tid; n < WBLK; n += 256) {
    int gi = T0 - 4000 + 8 * n;
    float v0, v1, v2, v3, v4, v5, v6, v7;
    if (gi >= 0 && gi + 8 <= T_LEN) {
      float4 a = *(const float4*)(xch + gi);
      float4 b = *(const float4*)(xch + gi + 4);
      v0 = a.x; v1 = a.y; v2 = a.z; v3 = a.w;
      v4 = b.x; v5 = b.y; v6 = b.z; v7 = b.w;
    } else {
      v0 = (gi + 0 >= 0 && gi + 0 < T_LEN) ? xch[gi + 0] : 0.f;
      v1 = (gi + 1 >= 0 && gi + 1 < T_LEN) ? xch[gi + 1] : 0.f;
      v2 = (gi + 2 >= 0 && gi + 2 < T_LEN) ? xch[gi + 2] : 0.f;
      v3 = (gi + 3 >= 0 && gi + 3 < T_LEN) ? xch[gi + 3] : 0.f;
      v4 = (gi + 4 >= 0 && gi + 4 < T_LEN) ? xch[gi + 4] : 0.f;
      v5 = (gi + 5 >= 0 && gi + 5 < T_LEN) ? xch[gi + 5] : 0.f;
      v6 = (gi + 6 >= 0 && gi + 6 < T_LEN) ? xch[gi + 6] : 0.f;
      v7 = (gi + 7 >= 0 && gi + 7 < T_LEN) ? xch[gi + 7] : 0.f;
    }
    uint4 pk;
    pk.x = (unsigned int)f2bf(v0) | ((unsigned int)f2bf(v1) << 16);
    pk.y = (unsigned int)f2bf(v2) | ((unsigned int)f2bf(v3) << 16);
    pk.z = (unsigned int)f2bf(v4) | ((unsigned int)f2bf(v5) << 16);
    pk.w = (unsigned int)f2bf(v6) | ((unsigned int)f2bf(v7) << 16);
    int sig = (n >> 5) + SIG_M * (n & 31);
    *(uint4*)(xs + 16 * sig) = pk;
  }
  __syncthreads();

  const int l31 = lane & 31;
  const int h = lane >> 5;
  const unsigned abase = 16u * (unsigned)l31;
  const int q0 = QSTEPS * w;

  // n = 32*l31 + s, s = 2q+h  ->  sigma = l31 + (s>>5) + 49*(s&31)
  auto aread = [&](int q) -> bf16x8 {
    unsigned s = 2u * (unsigned)q + (unsigned)h;
    unsigned off = 16u * ((s >> 5) + (unsigned)SIG_M * (s & 31));
    return *(const bf16x8*)(xs + abase + off);
  };
  auto bloadz = [&](int t) -> bf16x8 {
    int tc = ((unsigned)t > 252u) ? 252 : t;   // negatives & >252 -> T[252] = zeros
    return *(const bf16x8*)(btc + (size_t)tc * 1024 + lane * 16);
  };

  f32x16 acc[8] = {};
  // Ring prologue: at first E-step q0, need E_c = T[q0-2c]; O_c = T[q0+1-2c].
  bf16x8 E0 = bloadz(q0),     E1 = bloadz(q0 - 2), E2 = bloadz(q0 - 4), E3 = bloadz(q0 - 6),
         E4 = bloadz(q0 - 8), E5 = bloadz(q0 - 10), E6 = bloadz(q0 - 12), E7 = bloadz(q0 - 14);
  bf16x8 O0 = bloadz(q0 + 1), O1 = bloadz(q0 - 1), O2 = bloadz(q0 - 3), O3 = bloadz(q0 - 5),
         O4 = bloadz(q0 - 7), O5 = bloadz(q0 - 9), O6 = bloadz(q0 - 11), O7 = bloadz(q0 - 13);
  bf16x8 a_cur = aread(q0);

#define DO_STEP(R0, R1, R2, R3, R4, R5, R6, R7, QQ)                                      \
  {                                                                                      \
    bf16x8 nb = bloadz((QQ) + 2);                                                        \
    bf16x8 an = aread((QQ) + 1);                                                         \
    __builtin_amdgcn_s_setprio(1);                                                       \
    acc[0] = __builtin_amdgcn_mfma_f32_32x32x16_bf16(a_cur, R0, acc[0], 0, 0, 0);        \
    acc[1] = __builtin_amdgcn_mfma_f32_32x32x16_bf16(a_cur, R1, acc[1], 0, 0, 0);        \
    acc[2] = __builtin_amdgcn_mfma_f32_32x32x16_bf16(a_cur, R2, acc[2], 0, 0, 0);        \
    acc[3] = __builtin_amdgcn_mfma_f32_32x32x16_bf16(a_cur, R3, acc[3], 0, 0, 0);        \
    acc[4] = __builtin_amdgcn_mfma_f32_32x32x16_bf16(a_cur, R4, acc[4], 0, 0, 0);        \
    acc[5] = __builtin_amdgcn_mfma_f32_32x32x16_bf16(a_cur, R5, acc[5], 0, 0, 0);        \
    acc[6] = __builtin_amdgcn_mfma_f32_32x32x16_bf16(a_cur, R6, acc[6], 0, 0, 0);        \
    acc[7] = __builtin_amdgcn_mfma_f32_32x32x16_bf16(a_cur, R7, acc[7], 0, 0, 0);        \
    __builtin_amdgcn_s_setprio(0);                                                       \
    R7 = R6; R6 = R5; R5 = R4; R4 = R3; R3 = R2; R2 = R1; R1 = R0; R0 = nb;              \
    a_cur = an;                                                                          \
  }

#pragma unroll 8
  for (int qq = 0; qq < QSTEPS; qq += 2) {
    DO_STEP(E0, E1, E2, E3, E4, E5, E6, E7, q0 + qq);
    DO_STEP(O0, O1, O2, O3, O4, O5, O6, O7, q0 + qq + 1);
  }
#undef DO_STEP

  // ---- 4-way K-partial reduction through LDS (reuse A window region)
  __syncthreads();
  float* red = (float*)xs;   // 4 waves x 1024 f32 = 16 KB <= LDS_BYTES
  float* och = out + (size_t)ch * T_LEN + T0;
  const int ri = tid >> 3;        // output row i
  const int jg = tid & 7;         // 4-col group
#pragma unroll
  for (int c = 0; c < 8; ++c) {
#pragma unroll
    for (int r = 0; r < 16; ++r) {
      int irow = (r & 3) + 8 * (r >> 2) + 4 * h;
      red[w * 1024 + irow * 32 + l31] = acc[c][r];
    }
    __syncthreads();
    const float4* r4 = (const float4*)red;
    float4 s0 = r4[0 * 256 + ri * 8 + jg];
    float4 s1 = r4[1 * 256 + ri * 8 + jg];
    float4 s2 = r4[2 * 256 + ri * 8 + jg];
    float4 s3 = r4[3 * 256 + ri * 8 + jg];
    float4 sv;
    sv.x = (s0.x + s1.x) + (s2.x + s3.x);
    sv.y = (s0.y + s1.y) + (s2.y + s3.y);
    sv.z = (s0.z + s1.z) + (s2.z + s3.z);
    sv.w = (s0.w + s1.w) + (s2.w + s3.w);
    *(float4*)(och + 256 * ri + 32 * c + 4 * jg) = sv;
    __syncthreads();
  }
}

extern "C" void kernel_launch(void* const* d_in, const int* in_sizes, int n_in,
                              void* d_out, int out_size, void* d_ws, size_t ws_size,
                              hipStream_t stream) {
  const float* onsets  = (const float*)d_in[0];
  const float* sources = (const float*)d_in[1];
  unsigned short* btf  = (unsigned short*)d_ws;   // 64*253*64*8*2 = 16,580,608 B
  float* out = (float*)d_out;

  int nthr = NCH * NCHUNK * 64;
  build_btf<<<(nthr + 255) / 256, 256, 0, stream>>>(sources, btf);
  conv_main<<<NCH * 32, 256, 0, stream>>>(onsets, btf, out);
}

// Round 8
// 151.487 us; speedup vs baseline: 36.9547x; 36.9547x over previous
//
#include <hip/hip_runtime.h>

#define T_LEN 262144
#define R_LEN 4000
#define NCH 64
#define NCHUNK 253       // B chunks t in [0,253); T[252] = zeros (clamp target)
#define SIG_M 48         // sigma(n) = (n>>5) + 48*(n&31); n>>5 <= 47 -> injective
#define NSLOT 1536       // sigma range -> 1536 x 16B = 24576 B LDS
#define NSTEP 266        // q in [0,266) covers all taps r in [0,4000) for c in [0,8)

typedef __attribute__((ext_vector_type(8))) short bf16x8;
typedef __attribute__((ext_vector_type(16))) float f32x16;

static __device__ __forceinline__ unsigned short f2bf(float f) {
  unsigned u = __builtin_bit_cast(unsigned, f);
  unsigned r = 0x7FFFu + ((u >> 16) & 1u);
  return (unsigned short)((u + r) >> 16);
}

// T[t][j,h,e] = k[4000 + j - 16t - 8h - e] (zero outside [0,4000))
// stored: btf[((ch*253 + t)*64 + lane)*8 + e], j = lane&31, h = lane>>5
__global__ __launch_bounds__(256) void build_btf(const float* __restrict__ src,
                                                 unsigned short* __restrict__ btf) {
  int t0 = blockIdx.x * 256 + threadIdx.x;
  if (t0 >= NCH * NCHUNK * 64) return;
  int lane = t0 & 63;
  int t = (t0 >> 6) % NCHUNK;
  int ch = t0 / (64 * NCHUNK);
  int j = lane & 31;
  int h = lane >> 5;
  int kbase = 4000 + j - 16 * t - 8 * h;
  const float* k = src + (size_t)ch * R_LEN;
  unsigned short vals[8];
#pragma unroll
  for (int e = 0; e < 8; ++e) {
    int r = kbase - e;
    float f = (r >= 0 && r < R_LEN) ? k[r] : 0.0f;
    vals[e] = f2bf(f);
  }
  unsigned int* dst = (unsigned int*)(btf + (size_t)t0 * 8);
  dst[0] = (unsigned int)vals[0] | ((unsigned int)vals[1] << 16);
  dst[1] = (unsigned int)vals[2] | ((unsigned int)vals[3] << 16);
  dst[2] = (unsigned int)vals[4] | ((unsigned int)vals[5] << 16);
  dst[3] = (unsigned int)vals[6] | ((unsigned int)vals[7] << 16);
}

// ONE WAVE per block (64 thr). ch = bid&63 (all 32 pieces of a channel -> same XCD),
// piece = bid>>6, T0 = piece*8192. Outputs out[T0 + 256i + 32c + j], i,j in [0,32),
// c in [0,8). D_c[i][j] = sum_q A_q[i] . T[q-2c], A_q lane(i=l31,h):
// x[T0-4000+256i+16q+8h+e]. Window block n = 32i+2q+h staged at LDS slot
// sigma(n) = (n>>5)+48*(n&31): wave A-reads = 2 contiguous 512B segs (conflict-free).
// Barrier-light, 8-MFMA clusters, prefetch distance 2 (A: LDS, B: global/L2).
__global__ __launch_bounds__(64, 2) void conv_main(const float* __restrict__ x,
                                                   const unsigned short* __restrict__ btf,
                                                   float* __restrict__ out) {
  __shared__ alignas(16) unsigned char xs[NSLOT * 16];
  const int bid = blockIdx.x;
  const int ch = bid & 63;
  const int T0 = (bid >> 6) << 13;
  const float* xch = x + (size_t)ch * T_LEN;
  const char* btc = (const char*)btf + (size_t)ch * NCHUNK * 1024;

  const int lane = threadIdx.x;

  // ---- A staging: iterate permuted slot sig (contiguous LDS writes);
  // n = 32*(sig%48) + sig/48; global reads scattered (L2 absorbs).
  for (int sig = lane; sig < NSLOT; sig += 64) {
    int b = sig / 48;
    int a = sig - 48 * b;
    int n = 32 * a + b;
    int gi = T0 - 4000 + 8 * n;
    float v0, v1, v2, v3, v4, v5, v6, v7;
    if (gi >= 0 && gi + 8 <= T_LEN) {
      float4 va = *(const float4*)(xch + gi);
      float4 vb = *(const float4*)(xch + gi + 4);
      v0 = va.x; v1 = va.y; v2 = va.z; v3 = va.w;
      v4 = vb.x; v5 = vb.y; v6 = vb.z; v7 = vb.w;
    } else {
      v0 = (gi + 0 >= 0 && gi + 0 < T_LEN) ? xch[gi + 0] : 0.f;
      v1 = (gi + 1 >= 0 && gi + 1 < T_LEN) ? xch[gi + 1] : 0.f;
      v2 = (gi + 2 >= 0 && gi + 2 < T_LEN) ? xch[gi + 2] : 0.f;
      v3 = (gi + 3 >= 0 && gi + 3 < T_LEN) ? xch[gi + 3] : 0.f;
      v4 = (gi + 4 >= 0 && gi + 4 < T_LEN) ? xch[gi + 4] : 0.f;
      v5 = (gi + 5 >= 0 && gi + 5 < T_LEN) ? xch[gi + 5] : 0.f;
      v6 = (gi + 6 >= 0 && gi + 6 < T_LEN) ? xch[gi + 6] : 0.f;
      v7 = (gi + 7 >= 0 && gi + 7 < T_LEN) ? xch[gi + 7] : 0.f;
    }
    uint4 pk;
    pk.x = (unsigned int)f2bf(v0) | ((unsigned int)f2bf(v1) << 16);
    pk.y = (unsigned int)f2bf(v2) | ((unsigned int)f2bf(v3) << 16);
    pk.z = (unsigned int)f2bf(v4) | ((unsigned int)f2bf(v5) << 16);
    pk.w = (unsigned int)f2bf(v6) | ((unsigned int)f2bf(v7) << 16);
    *(uint4*)(xs + 16 * sig) = pk;
  }
  __syncthreads();   // single wave: compiles to waitcnt + trivial barrier

  const int l31 = lane & 31;
  const int h = lane >> 5;
  const unsigned abase = 16u * (unsigned)l31;

  // n = 32*l31 + s, s = 2q+h -> sigma = l31 + (s>>5) + 48*(s&31)
  auto aread = [&](int q) -> bf16x8 {
    unsigned s = 2u * (unsigned)q + (unsigned)h;
    unsigned off = 16u * ((s >> 5) + (unsigned)SIG_M * (s & 31));
    return *(const bf16x8*)(xs + abase + off);
  };
  auto bloadz = [&](int t) -> bf16x8 {
    int tc = ((unsigned)t > 252u) ? 252 : t;   // negatives & >252 -> T[252] = zeros
    return *(const bf16x8*)(btc + (size_t)tc * 1024 + lane * 16);
  };

  f32x16 acc[8] = {};
  // Ring state at step 0: E_c = T[-2c], O_c = T[1-2c] (clamp -> zeros for t<0)
  bf16x8 E0 = bloadz(0), E1 = bloadz(-2),  E2 = bloadz(-4),  E3 = bloadz(-6),
         E4 = bloadz(-8), E5 = bloadz(-10), E6 = bloadz(-12), E7 = bloadz(-14);
  bf16x8 O0 = bloadz(1), O1 = bloadz(-1),  O2 = bloadz(-3),  O3 = bloadz(-5),
         O4 = bloadz(-7), O5 = bloadz(-9), O6 = bloadz(-11), O7 = bloadz(-13);
  bf16x8 pE = bloadz(2), pO = bloadz(3);   // in-flight: T[q+2] for next same-parity step
  bf16x8 a_cur = aread(0), a_nxt = aread(1);

#define DO_STEP(R0, R1, R2, R3, R4, R5, R6, R7, PP, QQ)                                  \
  {                                                                                      \
    bf16x8 nb = bloadz((QQ) + 4);  /* for same-parity step after next */                 \
    bf16x8 an = aread((QQ) + 2);   /* A distance 2 */                                    \
    acc[0] = __builtin_amdgcn_mfma_f32_32x32x16_bf16(a_cur, R0, acc[0], 0, 0, 0);        \
    acc[1] = __builtin_amdgcn_mfma_f32_32x32x16_bf16(a_cur, R1, acc[1], 0, 0, 0);        \
    acc[2] = __builtin_amdgcn_mfma_f32_32x32x16_bf16(a_cur, R2, acc[2], 0, 0, 0);        \
    acc[3] = __builtin_amdgcn_mfma_f32_32x32x16_bf16(a_cur, R3, acc[3], 0, 0, 0);        \
    acc[4] = __builtin_amdgcn_mfma_f32_32x32x16_bf16(a_cur, R4, acc[4], 0, 0, 0);        \
    acc[5] = __builtin_amdgcn_mfma_f32_32x32x16_bf16(a_cur, R5, acc[5], 0, 0, 0);        \
    acc[6] = __builtin_amdgcn_mfma_f32_32x32x16_bf16(a_cur, R6, acc[6], 0, 0, 0);        \
    acc[7] = __builtin_amdgcn_mfma_f32_32x32x16_bf16(a_cur, R7, acc[7], 0, 0, 0);        \
    R7 = R6; R6 = R5; R5 = R4; R4 = R3; R3 = R2; R2 = R1; R1 = R0;                       \
    R0 = PP; PP = nb;                                                                    \
    a_cur = a_nxt; a_nxt = an;                                                           \
  }

#pragma unroll 4
  for (int q = 0; q < NSTEP; q += 2) {
    DO_STEP(E0, E1, E2, E3, E4, E5, E6, E7, pE, q);
    DO_STEP(O0, O1, O2, O3, O4, O5, O6, O7, pO, q + 1);
  }
#undef DO_STEP

  // C/D layout: col j = lane&31, row i = (r&3) + 8*(r>>2) + 4*h
  float* och = out + (size_t)ch * T_LEN + T0;
#pragma unroll
  for (int c = 0; c < 8; ++c) {
#pragma unroll
    for (int r = 0; r < 16; ++r) {
      int irow = (r & 3) + 8 * (r >> 2) + 4 * h;
      och[256 * irow + 32 * c + l31] = acc[c][r];
    }
  }
}

extern "C" void kernel_launch(void* const* d_in, const int* in_sizes, int n_in,
                              void* d_out, int out_size, void* d_ws, size_t ws_size,
                              hipStream_t stream) {
  const float* onsets  = (const float*)d_in[0];
  const float* sources = (const float*)d_in[1];
  unsigned short* btf  = (unsigned short*)d_ws;   // 64*253*64*8*2 = 16,580,608 B
  float* out = (float*)d_out;

  int nthr = NCH * NCHUNK * 64;
  build_btf<<<(nthr + 255) / 256, 256, 0, stream>>>(sources, btf);
  conv_main<<<NCH * 32, 64, 0, stream>>>(onsets, btf, out);
}